// Round 11
// baseline (183.632 us; speedup 1.0000x reference)
//
#include <hip/hip_runtime.h>
#include <math.h>

#define B_ 16
#define T_ 2048
#define D_ 256
#define W_ 128
#define M_ (B_*T_)   // 32768

typedef __attribute__((ext_vector_type(8))) short bf16x8;
typedef __attribute__((ext_vector_type(4))) float f32x4;
typedef unsigned short u16;

static __device__ __forceinline__ u16 f32_bf16_rne(float f) {
    unsigned int u = __float_as_uint(f);
    u += 0x7FFF + ((u >> 16) & 1);
    return (u16)(u >> 16);
}
static __device__ __forceinline__ float bf16_f32(u16 h) {
    return __uint_as_float(((unsigned int)h) << 16);
}
// async global->LDS, 16B per lane.  LDS dest = wave-uniform base + lane*16.
static __device__ __forceinline__ void gload_lds16(const u16* g, u16* l) {
    __builtin_amdgcn_global_load_lds(
        (const __attribute__((address_space(1))) void*)g,
        (__attribute__((address_space(3))) void*)l, 16, 0, 0);
}

// ---------------------------------------------------------------------------
// K0: merged prep (R11) -- one dispatch replaces aft_split_wT + aft_ewb.
// blocks [0,2048): EWb precompute; blocks [2048,2112): weight transpose.
// ---------------------------------------------------------------------------
__global__ __launch_bounds__(320) void aft_prep(
    const float* __restrict__ Wq, const float* __restrict__ Wk,
    const float* __restrict__ Wv, const float* __restrict__ Wo,
    const float* __restrict__ wb,
    u16* __restrict__ Wth, u16* __restrict__ Wkl, u16* __restrict__ EWb)
{
    const int tid = threadIdx.x;
    if (blockIdx.x < 2048) {
        // EWb[t][j], j in [0,320): exp(wb[t][s])-1 inside band else 0,
        // s = (t & ~63) - 128 + j.  bf16.
        const int t = blockIdx.x;
        const int j = tid;   // 320 threads
        const int s = (t & ~63) - 128 + j;
        const int dlt = s - t;
        float v = 0.f;
        if (s >= 0 && s < T_ && dlt > -W_ && dlt < W_)
            v = expf(wb[(size_t)t * T_ + s]) - 1.0f;
        EWb[(size_t)t * 320 + j] = f32_bf16_rne(v);
        return;
    }
    // weight transpose: bf16 [mat][n][k]; hi all 4 mats, lo for Wk only.
    __shared__ alignas(16) u16 Th[64][72];
    __shared__ alignas(16) u16 Tl[64][72];
    const int bid = blockIdx.x - 2048;     // 0..63
    const int mat = bid >> 4;
    const float* Ws[4] = {Wq, Wk, Wv, Wo};
    const float* W = Ws[mat];
    const int k0 = (bid & 3) * 64;
    const int n0 = ((bid >> 2) & 3) * 64;

    if (tid < 256) {
        #pragma unroll
        for (int p = 0; p < 4; ++p) {
            const int k = p * 16 + (tid >> 4);
            const int n = (tid & 15) * 4;
            float4 v = *(const float4*)&W[(size_t)(k0 + k) * 256 + n0 + n];
            float vv[4] = {v.x, v.y, v.z, v.w};
            #pragma unroll
            for (int e = 0; e < 4; ++e) {
                u16 h = f32_bf16_rne(vv[e]);
                Th[n + e][k] = h;
                Tl[n + e][k] = f32_bf16_rne(vv[e] - bf16_f32(h));
            }
        }
    }
    __syncthreads();
    if (tid < 256) {
        const int n  = tid >> 2;
        const int kc = (tid & 3) * 16;
        size_t ob = ((size_t)mat * 256 + n0 + n) * 256 + k0 + kc;
        *(uint4*)&Wth[ob]     = *(const uint4*)&Th[n][kc];
        *(uint4*)&Wth[ob + 8] = *(const uint4*)&Th[n][kc + 8];
        if (mat == 1) {
            size_t ol = ((size_t)(n0 + n)) * 256 + k0 + kc;
            *(uint4*)&Wkl[ol]     = *(const uint4*)&Tl[n][kc];
            *(uint4*)&Wkl[ol + 8] = *(const uint4*)&Tl[n][kc + 8];
        }
    }
}

// ---------------------------------------------------------------------------
// K1: QKV projections (R5/R7 main loop, measured plateau 46.5us).  Epilogue
// also emits per-(row, t-block) partial sums of ek/ekv into Skp (f32),
// [tblk][row] layout (coalesced, R10).
// ---------------------------------------------------------------------------
__global__ __launch_bounds__(256, 3) void aft_qkv_mfma(
    const float* __restrict__ x,
    const u16* __restrict__ Wth, const u16* __restrict__ Wkl,
    u16* __restrict__ ekT, u16* __restrict__ sigqT, float* __restrict__ Skp)
{
    // main loop: Ah[64][32] + Al[64][32] + Bs[4][64][32] = 12288 u16 (24KB)
    // epilogue:  Tr[64][72] = 4608 u16 reuses the same space
    __shared__ alignas(16) u16 sm[12288];
    u16* Ah = sm;               // [64][32]
    u16* Al = sm + 2048;        // [64][32]
    u16* Bs = sm + 4096;        // [4][64][32]: Wqh, Wkh, Wkl, Wvh
    u16* Tr = sm;               // [64][72] epilogue reuse

    const int tid  = threadIdx.x;
    const int row0 = blockIdx.x * 64;
    const int col0 = blockIdx.y * 64;
    const int b    = row0 >> 11;
    const int t0g  = row0 & (T_ - 1);
    const int tblk = blockIdx.x & 31;    // t-block index within batch b
    const int lane = tid & 63;
    const int wid  = tid >> 6;           // 0..3
    const int wm   = (wid >> 1) * 32;    // 2 M-groups of 32
    const int wn   = (wid & 1) * 32;     // 2 N-groups of 32
    const int qd   = lane >> 4;
    const int r    = lane & 15;

    f32x4 accq[2][2], acck[2][2], accv[2][2];
    #pragma unroll
    for (int i = 0; i < 2; ++i)
        #pragma unroll
        for (int j = 0; j < 2; ++j) {
            accq[i][j] = (f32x4){0.f, 0.f, 0.f, 0.f};
            acck[i][j] = accq[i][j];
            accv[i][j] = accq[i][j];
        }

    // staging coords: 256 threads cover 64 rows x 32 cols (4 chunks of 8 u16)
    const int crow  = tid >> 2;                 // 0..63
    const int gchk  = tid & 3;                  // this thread's global chunk
    const int cswz  = (crow >> 1) & 3;          // row-dependent chunk XOR
    const int ccols = (gchk ^ cswz) * 8;        // pre-swizzled SOURCE col (B)
    const int aslot = crow * 32 + (gchk ^ cswz) * 8;  // swizzled LDS slot (A)
    const int wbase = wid * 512;                // gload dest: wave chunk (u16)
    // fragment-read slot with the matching XOR (verified R3: conflicts ~0)
    const int sq8   = (qd ^ ((r >> 1) & 3)) * 8;

    for (int k0 = 0; k0 < D_; k0 += 32) {
        if (k0) __syncthreads();          // compute(k-1) reads done
        // stage B: 4 tensors x 64 rows, linear dest + swizzled source
        {
            size_t gb = (size_t)(col0 + crow) * 256 + k0 + ccols;
            gload_lds16(&Wth[gb],          &Bs[0 * 2048 + wbase]);
            gload_lds16(&Wth[65536 + gb],  &Bs[1 * 2048 + wbase]);
            gload_lds16(&Wkl[gb],          &Bs[2 * 2048 + wbase]);
            gload_lds16(&Wth[131072 + gb], &Bs[3 * 2048 + wbase]);
        }
        // stage A: x fp32 -> bf16 hi/lo in-register -> swizzled ds_write
        // (source col UNswizzled gchk*8, dest slot swizzled -- rule #21)
        {
            size_t ga = (size_t)(row0 + crow) * 256 + k0 + gchk * 8;
            float4 v0 = *(const float4*)&x[ga];
            float4 v1 = *(const float4*)&x[ga + 4];
            float vv[8] = {v0.x, v0.y, v0.z, v0.w, v1.x, v1.y, v1.z, v1.w};
            union { uint4 q; u16 h[8]; } H, L;
            #pragma unroll
            for (int e = 0; e < 8; ++e) {
                u16 h = f32_bf16_rne(vv[e]);
                H.h[e] = h;
                L.h[e] = f32_bf16_rne(vv[e] - bf16_f32(h));
            }
            *(uint4*)&Ah[aslot] = H.q;
            *(uint4*)&Al[aslot] = L.q;
        }
        __syncthreads();                  // drains vmcnt (B) + lgkm (A writes)

        bf16x8 ah[2], al[2];
        #pragma unroll
        for (int mf = 0; mf < 2; ++mf) {
            int ar = (wm + mf * 16 + r) * 32 + sq8;
            ah[mf] = *(const bf16x8*)&Ah[ar];
            al[mf] = *(const bf16x8*)&Al[ar];
        }
        #pragma unroll
        for (int nf = 0; nf < 2; ++nf) {
            int br = (wn + nf * 16 + r) * 32 + sq8;
            bf16x8 bq  = *(const bf16x8*)&Bs[br];
            bf16x8 bkh = *(const bf16x8*)&Bs[2048 + br];
            bf16x8 bkl = *(const bf16x8*)&Bs[4096 + br];
            bf16x8 bv  = *(const bf16x8*)&Bs[6144 + br];
            #pragma unroll
            for (int mf = 0; mf < 2; ++mf) {
                accq[mf][nf] = __builtin_amdgcn_mfma_f32_16x16x32_bf16(ah[mf], bq,  accq[mf][nf], 0, 0, 0);
                acck[mf][nf] = __builtin_amdgcn_mfma_f32_16x16x32_bf16(ah[mf], bkh, acck[mf][nf], 0, 0, 0);
                acck[mf][nf] = __builtin_amdgcn_mfma_f32_16x16x32_bf16(ah[mf], bkl, acck[mf][nf], 0, 0, 0);
                acck[mf][nf] = __builtin_amdgcn_mfma_f32_16x16x32_bf16(al[mf], bkh, acck[mf][nf], 0, 0, 0);
                accv[mf][nf] = __builtin_amdgcn_mfma_f32_16x16x32_bf16(ah[mf], bv,  accv[mf][nf], 0, 0, 0);
            }
        }
    }

    // epilogue: 3 LDS-transpose rounds (ek, ekv, sigq) -> global bf16.
    // rounds 0/1 also emit f32 partial row-sums (over this block's 64 t).
    const int dl_r = tid >> 2;            // 0..63
    const int tseg = (tid & 3) * 16;      // 0..48
    #pragma unroll
    for (int round = 0; round < 3; ++round) {
        __syncthreads();
        #pragma unroll
        for (int mf = 0; mf < 2; ++mf) {
            #pragma unroll
            for (int nf = 0; nf < 2; ++nf) {
                ushort4 o;
                float vals[4];
                #pragma unroll
                for (int reg = 0; reg < 4; ++reg) {
                    if (round == 0)      vals[reg] = expf(acck[mf][nf][reg]);
                    else if (round == 1) vals[reg] = expf(acck[mf][nf][reg]) * accv[mf][nf][reg];
                    else                 vals[reg] = 1.f / (1.f + expf(-accq[mf][nf][reg]));
                }
                o.x = f32_bf16_rne(vals[0]); o.y = f32_bf16_rne(vals[1]);
                o.z = f32_bf16_rne(vals[2]); o.w = f32_bf16_rne(vals[3]);
                int dl = wn + nf * 16 + r;
                int tt = wm + mf * 16 + qd * 4;
                *(ushort4*)&Tr[dl * 72 + tt] = o;
            }
        }
        __syncthreads();
        u16* dst;
        if (round == 0)      dst = ekT   + ((size_t)(b * 512 + col0 + dl_r)) * 2048;
        else if (round == 1) dst = ekT   + ((size_t)(b * 512 + 256 + col0 + dl_r)) * 2048;
        else                 dst = sigqT + ((size_t)(b * 256 + col0 + dl_r)) * 2048;
        dst += t0g + tseg;
        const u16* srcp = &Tr[dl_r * 72 + tseg];
        uint4 q0 = *(const uint4*)&srcp[0];
        uint4 q1 = *(const uint4*)&srcp[8];
        *(uint4*)&dst[0] = q0;
        *(uint4*)&dst[8] = q1;
        if (round < 2) {
            const u16* h0 = (const u16*)&q0;
            const u16* h1 = (const u16*)&q1;
            float s = 0.f;
            #pragma unroll
            for (int i = 0; i < 8; ++i) s += bf16_f32(h0[i]);
            #pragma unroll
            for (int i = 0; i < 8; ++i) s += bf16_f32(h1[i]);
            s += __shfl_down(s, 1, 64);   // 4 threads per row -> tree reduce
            s += __shfl_down(s, 2, 64);
            if ((tid & 3) == 0)
                Skp[(size_t)tblk * 8192 + (b * 512 + round * 256 + col0 + dl_r)] = s;
        }
    }
}

// ---------------------------------------------------------------------------
// K2: reduce K1's partials (1MB) -> Sk (n<256), Sv (n>=256).  Coalesced
// [tblk][row] reads; ascending-tblk order (bit-identical to R9/R10).
// ---------------------------------------------------------------------------
__global__ __launch_bounds__(256) void aft_sums2(
    const float* __restrict__ Skp, float* __restrict__ Sk, float* __restrict__ Sv)
{
    const int row = blockIdx.x * 256 + threadIdx.x;   // 0..8191
    float s = 0.f;
    #pragma unroll 8
    for (int c = 0; c < 32; ++c)
        s += Skp[(size_t)c * 8192 + row];
    const int b = row >> 9, n = row & 511;
    if (n < 256) Sk[b * 256 + n] = s;
    else         Sv[b * 256 + n - 256] = s;
}

// ---------------------------------------------------------------------------
// K3+K4 fused (R11): aft_band_out.  Block = 64 t x FULL 256 d, 512 threads.
// Phase 1: banded num/den (64t x 256d), wave tile 32t x 64d (acc 64 regs).
//   B = ek/ekv 512 rows via gload_lds (swizzled source); A = EWb via
//   reg+ds_write (unswizzled source, swizzled dest).  For 64-t tiles the
//   EWb window index is j = c*32, always in [0,320) -- no window check.
// Phase 2: y = sig(q)*(Sv+num)/(Sk+den) -> LDS Ly[64][264] bf16 (padded
//   stride: 33 16B-chunks/row -> conflict-free b128 reads; values
//   bit-identical to the old yTD path).
// Phase 3: out = y @ Wo.  A read DIRECTLY from Ly (no staging); Wo staged
//   per k-step via gload_lds.  Kills the 33.5MB yTD round-trip + 1 dispatch.
// ---------------------------------------------------------------------------
__global__ __launch_bounds__(512, 2) void aft_band_out(
    const u16* __restrict__ EWb, const u16* __restrict__ ekT,
    const u16* __restrict__ sigqT,
    const float* __restrict__ Sk, const float* __restrict__ Sv,
    const u16* __restrict__ Woth, float* __restrict__ out)
{
    // phase 1: Aw[64][32] @0 (2048) + Bkv[512][32] @2048 (16384)  = 36 KB
    // phase 2/3: Ly[64][264] @0 (16896) + Bw[256][32] @16896 (8192) = 49 KB
    __shared__ alignas(16) u16 sm[25088];
    u16* Aw  = sm;            // [64][32] swizzled
    u16* Bkv = sm + 2048;     // [512][32]: rows 0..255 ek, 256..511 ekv
    u16* Ly  = sm;            // [64][264]
    u16* Bw  = sm + 16896;    // [256][32]

    const int tid  = threadIdx.x;        // 0..511
    const int t0   = blockIdx.x * 64;
    const int b    = blockIdx.y;
    const int lane = tid & 63;
    const int wid  = tid >> 6;           // 0..7
    const int tw   = wid >> 2;           // t-half (0/1) of 32
    const int dw   = wid & 3;            // d-quarter (64 each)
    const int qd   = lane >> 4;
    const int r    = lane & 15;

    f32x4 accn[2][4], accd[2][4];        // 64 VGPRs
    #pragma unroll
    for (int i = 0; i < 2; ++i)
        #pragma unroll
        for (int j = 0; j < 4; ++j) {
            accn[i][j] = (f32x4){0.f, 0.f, 0.f, 0.f};
            accd[i][j] = (f32x4){0.f, 0.f, 0.f, 0.f};
        }

    // staging coords: crow 0..127 covers 128 rows x 32 cols per issue
    const int crow  = tid >> 2;                 // 0..127
    const int gchk  = tid & 3;
    const int cswz  = (crow >> 1) & 3;
    const int ccols = (gchk ^ cswz) * 8;        // pre-swizzled SOURCE col (B)
    const int wbase = wid * 512;                // gload dest: wave chunk (u16)
    const int sq8   = (qd ^ ((r >> 1) & 3)) * 8;

    // ---------------- phase 1: banded num/den ----------------
    for (int c = 0; c < 10; ++c) {
        const int sc = t0 - 128 + c * 32;
        if (sc < 0 || sc >= T_) continue;   // uniform per block
        __syncthreads();                    // prior compute's ds_reads done
        // stage B: 512 rows (ek 0..255, ekv 256..511), 4 issues of 128 rows
        #pragma unroll
        for (int rr = 0; rr < 4; ++rr) {
            int row = rr * 128 + crow;      // 0..511 == n offset within b
            gload_lds16(&ekT[((size_t)(b * 512) + row) * 2048 + sc + ccols],
                        &Bkv[rr * 4096 + wbase]);
        }
        // stage A: EWb 64 rows x 32 cols (threads 0..255); j = c*32 always
        // in-window for 64-t tiles.  Unswizzled source, swizzled dest.
        if (tid < 256) {
            const int arow = tid >> 2;      // 0..63
            const int agk  = tid & 3;
            uint4 v = *(const uint4*)&EWb[(size_t)(t0 + arow) * 320 + c * 32 + agk * 8];
            *(uint4*)&Aw[arow * 32 + ((agk ^ ((arow >> 1) & 3))) * 8] = v;
        }
        __syncthreads();                    // vmcnt(0) + lgkm drain

        bf16x8 af[2];
        #pragma unroll
        for (int mf = 0; mf < 2; ++mf)
            af[mf] = *(const bf16x8*)&Aw[(tw * 32 + mf * 16 + r) * 32 + sq8];
        #pragma unroll
        for (int nf = 0; nf < 4; ++nf) {
            int dr = dw * 64 + nf * 16 + r;
            bf16x8 be = *(const bf16x8*)&Bkv[dr * 32 + sq8];
            bf16x8 bv = *(const bf16x8*)&Bkv[(256 + dr) * 32 + sq8];
            #pragma unroll
            for (int mf = 0; mf < 2; ++mf) {
                accd[mf][nf] = __builtin_amdgcn_mfma_f32_16x16x32_bf16(af[mf], be, accd[mf][nf], 0, 0, 0);
                accn[mf][nf] = __builtin_amdgcn_mfma_f32_16x16x32_bf16(af[mf], bv, accn[mf][nf], 0, 0, 0);
            }
        }
    }

    // ---------------- phase 2: y -> Ly[64][264] ----------------
    __syncthreads();        // all phase-1 LDS reads done before overwrite
    #pragma unroll
    for (int nf = 0; nf < 4; ++nf) {
        const int d = dw * 64 + nf * 16 + r;
        const float skq = Sk[(b << 8) + d];
        const float svq = Sv[(b << 8) + d];
        #pragma unroll
        for (int mf = 0; mf < 2; ++mf) {
            const int ttl = tw * 32 + mf * 16 + qd * 4;   // 0..63 local t
            size_t off = ((size_t)(b << 8) + d) * 2048 + t0 + ttl;
            ushort4 sg = *(const ushort4*)&sigqT[off];
            float s4[4] = {bf16_f32(sg.x), bf16_f32(sg.y), bf16_f32(sg.z), bf16_f32(sg.w)};
            #pragma unroll
            for (int reg = 0; reg < 4; ++reg) {
                float y = s4[reg] * (svq + accn[mf][nf][reg]) / (skq + accd[mf][nf][reg]);
                Ly[(ttl + reg) * 264 + d] = f32_bf16_rne(y);
            }
        }
    }

    // ---------------- phase 3: out = y @ Wo ----------------
    f32x4 acc3[2][4];       // 32 VGPRs (phase-1 acc dead)
    #pragma unroll
    for (int i = 0; i < 2; ++i)
        #pragma unroll
        for (int j = 0; j < 4; ++j)
            acc3[i][j] = (f32x4){0.f, 0.f, 0.f, 0.f};

    const int we = dw * 64;   // wave's e-quarter
    for (int k0 = 0; k0 < D_; k0 += 32) {
        __syncthreads();      // k0=0: Ly writes visible; k0>0: Bw reads done
        // stage Wo: 256 e-rows x 32 k (2 issues of 128 rows)
        #pragma unroll
        for (int rr = 0; rr < 2; ++rr) {
            int row = rr * 128 + crow;
            gload_lds16(&Woth[(size_t)row * 256 + k0 + ccols],
                        &Bw[rr * 4096 + wbase]);
        }
        __syncthreads();      // Bw landed

        bf16x8 af[2];
        #pragma unroll
        for (int mf = 0; mf < 2; ++mf)
            af[mf] = *(const bf16x8*)&Ly[(tw * 32 + mf * 16 + r) * 264 + k0 + qd * 8];
        #pragma unroll
        for (int nf = 0; nf < 4; ++nf) {
            bf16x8 bh = *(const bf16x8*)&Bw[(we + nf * 16 + r) * 32 + sq8];
            #pragma unroll
            for (int mf = 0; mf < 2; ++mf)
                acc3[mf][nf] = __builtin_amdgcn_mfma_f32_16x16x32_bf16(af[mf], bh, acc3[mf][nf], 0, 0, 0);
        }
    }

    #pragma unroll
    for (int mf = 0; mf < 2; ++mf)
        #pragma unroll
        for (int nf = 0; nf < 4; ++nf)
            #pragma unroll
            for (int reg = 0; reg < 4; ++reg) {
                int mrow = b * 2048 + t0 + tw * 32 + mf * 16 + qd * 4 + reg;
                int ncol = we + nf * 16 + r;
                out[(size_t)mrow * D_ + ncol] = acc3[mf][nf][reg];
            }
}

extern "C" void kernel_launch(void* const* d_in, const int* in_sizes, int n_in,
                              void* d_out, int out_size, void* d_ws, size_t ws_size,
                              hipStream_t stream)
{
    const float* x  = (const float*)d_in[0];
    const float* Wq = (const float*)d_in[1];
    const float* Wk = (const float*)d_in[2];
    const float* Wv = (const float*)d_in[3];
    const float* Wo = (const float*)d_in[4];
    const float* wb = (const float*)d_in[5];
    // window (d_in[6]) is the constant 128, baked in as W_.

    u16* Wth   = (u16*)d_ws;                 // 4*65536 = 262144
    u16* Wkl   = Wth + 262144;               // 65536
    u16* EWb   = Wkl + 65536;                // 655360
    u16* ekT   = EWb + 655360;               // 16777216
    u16* sigqT = ekT + 16777216;             // 8388608
    float* Sk  = (float*)(sigqT + 8388608);  // 4096
    float* Sv  = Sk + 4096;                  // 4096
    float* Skp = Sv + 4096;                  // 32*8192 = 262144 (1MB)

    aft_prep<<<dim3(2112), 320, 0, stream>>>(Wq, Wk, Wv, Wo, wb, Wth, Wkl, EWb);
    aft_qkv_mfma<<<dim3(M_ / 64, 4), 256, 0, stream>>>(x, Wth, Wkl, ekT, sigqT, Skp);
    aft_sums2<<<dim3(32), 256, 0, stream>>>(Skp, Sk, Sv);
    aft_band_out<<<dim3(T_ / 64, B_), 512, 0, stream>>>(EWb, ekT, sigqT, Sk, Sv,
                                                        Wth + 3 * 65536, (float*)d_out);
}